// Round 5
// baseline (2399.400 us; speedup 1.0000x reference)
//
#include <hip/hip_runtime.h>
#include <cmath>

// Mamba_TransformerEncoder on MI355X (gfx950).
// B=4, L=512, D=512, NH=8, HD=64, FF=2048, NL=4, DI=1024, DS=64, DC=4, DTR=32.
// R5: (1) gemm128_kernel -- 128x128 tile, 4 waves, BK=32, global_load_lds(16B) staging
// into fragment-order LDS layout [ko][row][8]; replaces the single-wave 64x64 GEMM for
// all rectangular GEMMs. (2) scan_p3 two-section 32-row LDS buffer (8.3KB/wave) to lift
// occupancy 20%->~55%. Attention batched GEMMs (S, PV) stay on the old gemm kernel.

typedef __attribute__((ext_vector_type(8))) __bf16 bf16x8;
typedef __attribute__((ext_vector_type(4))) __bf16 bf16x4;
typedef __attribute__((ext_vector_type(4))) float f32x4;

#define DEV static __device__ __forceinline__

#define LDS_PTR(p) ((__attribute__((address_space(3))) void*)(p))
#define GLB_PTR(p) ((const __attribute__((address_space(1))) void*)(p))

DEV float wave_sum(float x) {
#pragma unroll
  for (int o = 32; o; o >>= 1) x += __shfl_xor(x, o, 64);
  return x;
}
DEV float wave_max(float x) {
#pragma unroll
  for (int o = 32; o; o >>= 1) x = fmaxf(x, __shfl_xor(x, o, 64));
  return x;
}

// ---------------- fp32 -> bf16 convert (x4 vectorized) ----------------
__global__ void cvt_kernel(const float* __restrict__ s, __bf16* __restrict__ d, int n4) {
  int i = blockIdx.x * 256 + threadIdx.x;
  if (i < n4) {
    float4 v = ((const float4*)s)[i];
    bf16x4 r = {(__bf16)v.x, (__bf16)v.y, (__bf16)v.z, (__bf16)v.w};
    *(bf16x4*)(d + (size_t)i * 4) = r;
  }
}

// ---------------- positional encoding + bf16 cast ----------------
__global__ void pe_kernel(const float* __restrict__ src, __bf16* __restrict__ xb) {
  int idx = blockIdx.x * 256 + threadIdx.x;  // B*L*D = 1048576
  int d = idx & 511;
  int l = (idx >> 9) & 511;
  float ang = (float)l * expf((float)(d & ~1) * (-9.210340371976184f / 512.f));
  float pe = (d & 1) ? cosf(ang) : sinf(ang);
  xb[idx] = (__bf16)(src[idx] + pe);
}

// ============ old single-wave 64x64 GEMM (kept for batched attention S / PV) ============
struct GemmArgs {
  const __bf16* A; const __bf16* W;
  const float* bias; const float* add;
  float* Cf; __bf16* Cb;
  long long sAzb, sAzh, sWzb, sWzh, sADzb, sADzh, sCfzb, sCfzh, sCbzb, sCbzh;
  int lda, ldw, ldad, ldcf, ldcb;
  int M, N, K, ZH;
  float alpha; int act;  // 0 none, 1 relu, 2 softplus
  int ct;
};

__global__ __launch_bounds__(64) void gemm_kernel(GemmArgs g) {
  const int lane = threadIdx.x;
  const int m0 = blockIdx.x * 64, n0 = blockIdx.y * 64;
  const int zb = blockIdx.z / g.ZH, zh = blockIdx.z % g.ZH;
  const __bf16* A = g.A + zb * g.sAzb + zh * g.sAzh;
  const __bf16* W = g.W + zb * g.sWzb + zh * g.sWzh;
  const int fr = lane & 15;
  const int fk = (lane >> 4) * 8;
  const __bf16* pa[4]; const __bf16* pw[4];
#pragma unroll
  for (int i = 0; i < 4; ++i) {
    int ra = m0 + i * 16 + fr;
    pa[i] = A + (size_t)ra * g.lda + fk;
    int rw = n0 + i * 16 + fr; if (rw > g.N - 1) rw = g.N - 1;
    pw[i] = W + (size_t)rw * g.ldw + fk;
  }
  f32x4 acc[4][4] = {};
  for (int k0 = 0; k0 < g.K; k0 += 32) {
    bf16x8 af[4], wf[4];
#pragma unroll
    for (int i = 0; i < 4; ++i) af[i] = *(const bf16x8*)(pa[i] + k0);
#pragma unroll
    for (int j = 0; j < 4; ++j) wf[j] = *(const bf16x8*)(pw[j] + k0);
#pragma unroll
    for (int i = 0; i < 4; ++i)
#pragma unroll
      for (int j = 0; j < 4; ++j)
        acc[i][j] = __builtin_amdgcn_mfma_f32_16x16x32_bf16(af[i], wf[j], acc[i][j], 0, 0, 0);
  }
  const float* addp = g.add ? g.add + zb * g.sADzb + zh * g.sADzh : nullptr;
  float* cf = g.Cf ? g.Cf + zb * g.sCfzb + zh * g.sCfzh : nullptr;
  __bf16* cb = g.Cb ? g.Cb + zb * g.sCbzb + zh * g.sCbzh : nullptr;
  const int rbase = m0 + (lane >> 4) * 4;
#pragma unroll
  for (int i = 0; i < 4; ++i) {
#pragma unroll
    for (int j = 0; j < 4; ++j) {
      int col = n0 + j * 16 + fr;
      if (col < g.N) {
#pragma unroll
        for (int r = 0; r < 4; ++r) {
          int row = rbase + i * 16 + r;
          float v = acc[i][j][r] * g.alpha;
          if (g.bias) v += g.bias[col];
          if (addp) v += addp[(size_t)row * g.ldad + col];
          if (g.act == 1) v = fmaxf(v, 0.f);
          else if (g.act == 2) v = (v > 20.f) ? v : log1pf(expf(v));
          if (cf) {
            if (g.ct) cf[(size_t)col * g.ldcf + row] = v;
            else      cf[(size_t)row * g.ldcf + col] = v;
          }
          if (cb) cb[(size_t)row * g.ldcb + col] = (__bf16)v;
        }
      }
    }
  }
}

static void launch_gemm(hipStream_t st,
    const __bf16* A, int lda, long long sAzb, long long sAzh,
    const __bf16* W, int ldw, long long sWzb, long long sWzh,
    const float* bias,
    const float* add, int ldad, long long sADzb, long long sADzh,
    float* Cf, int ldcf, long long sCfzb, long long sCfzh,
    __bf16* Cb, int ldcb, long long sCbzb, long long sCbzh,
    int M, int N, int K, int Z, int ZH, float alpha, int act, int ct = 0) {
  GemmArgs g;
  g.A = A; g.W = W; g.bias = bias; g.add = add; g.Cf = Cf; g.Cb = Cb;
  g.sAzb = sAzb; g.sAzh = sAzh; g.sWzb = sWzb; g.sWzh = sWzh;
  g.sADzb = sADzb; g.sADzh = sADzh; g.sCfzb = sCfzb; g.sCfzh = sCfzh;
  g.sCbzb = sCbzb; g.sCbzh = sCbzh;
  g.lda = lda; g.ldw = ldw; g.ldad = ldad; g.ldcf = ldcf; g.ldcb = ldcb;
  g.M = M; g.N = N; g.K = K; g.ZH = ZH; g.alpha = alpha; g.act = act; g.ct = ct;
  dim3 grid(M / 64, (N + 63) / 64, Z);
  gemm_kernel<<<grid, 64, 0, st>>>(g);
}

// ============ 128x128 LDS-staged 4-wave GEMM (m97-style) ============
// C = act(alpha*(A @ W^T) + bias + add). A:(M,K), W:(N,K) bf16 K-contig.
// LDS layout (fragment-order): As[ko][row][8] bf16, ko=0..3 (k-oct), row=0..127.
// Staging: wave w issues global_load_lds(16B) for seg {2w, 2w+1}: lane i of seg s
// covers LDS elems s*512 + i*8 = (ko=s>>1, row=(s&1)*64+i) -> linear lane map holds.
// Fragment ds_read_b128 at fk*1024 + row*8 spreads all 8 bank-groups (conflict-free).
struct Gemm128Args {
  const __bf16* A; const __bf16* W;
  const float* bias; const float* add;
  float* Cf; __bf16* Cb;
  int lda, ldw, ldad, ldcf, ldcb;
  int M, N, K;
  float alpha; int act; int ct;
};

__global__ __launch_bounds__(256) void gemm128_kernel(Gemm128Args g) {
  __shared__ __align__(16) __bf16 As[4096];
  __shared__ __align__(16) __bf16 Bs[4096];
  const int tid = threadIdx.x;
  const int lane = tid & 63;
  const int wid = tid >> 6;
  const int m0 = blockIdx.x * 128, n0 = blockIdx.y * 128;
  const int fr = lane & 15;
  const int fk = lane >> 4;
  // staging global pointers (wave wid stages ko=wid for rows 0..63 and 64..127)
  const __bf16* gA0 = g.A + (size_t)(m0 + lane) * g.lda + wid * 8;
  const __bf16* gA1 = g.A + (size_t)(m0 + 64 + lane) * g.lda + wid * 8;
  int rb0 = n0 + lane; if (rb0 > g.N - 1) rb0 = g.N - 1;
  int rb1 = n0 + 64 + lane; if (rb1 > g.N - 1) rb1 = g.N - 1;
  const __bf16* gW0 = g.W + (size_t)rb0 * g.ldw + wid * 8;
  const __bf16* gW1 = g.W + (size_t)rb1 * g.ldw + wid * 8;
  __bf16* lA0 = As + wid * 1024;
  __bf16* lA1 = As + wid * 1024 + 512;
  __bf16* lB0 = Bs + wid * 1024;
  __bf16* lB1 = Bs + wid * 1024 + 512;
  // fragment LDS read bases
  const int arow = (wid >> 1) * 64 + fr;
  const int brow = (wid & 1) * 64 + fr;
  const __bf16* a_lds = As + fk * 1024 + arow * 8;
  const __bf16* b_lds = Bs + fk * 1024 + brow * 8;

  f32x4 acc[4][4] = {};
  for (int k0 = 0; k0 < g.K; k0 += 32) {
    __syncthreads();  // previous iteration's frag reads done before overwrite
    __builtin_amdgcn_global_load_lds(GLB_PTR(gA0 + k0), LDS_PTR(lA0), 16, 0, 0);
    __builtin_amdgcn_global_load_lds(GLB_PTR(gA1 + k0), LDS_PTR(lA1), 16, 0, 0);
    __builtin_amdgcn_global_load_lds(GLB_PTR(gW0 + k0), LDS_PTR(lB0), 16, 0, 0);
    __builtin_amdgcn_global_load_lds(GLB_PTR(gW1 + k0), LDS_PTR(lB1), 16, 0, 0);
    __syncthreads();  // vmcnt(0) drained by compiler before barrier -> tiles visible
    bf16x8 af[4], wf[4];
#pragma unroll
    for (int i = 0; i < 4; ++i) af[i] = *(const bf16x8*)(a_lds + i * 128);
#pragma unroll
    for (int j = 0; j < 4; ++j) wf[j] = *(const bf16x8*)(b_lds + j * 128);
#pragma unroll
    for (int i = 0; i < 4; ++i)
#pragma unroll
      for (int j = 0; j < 4; ++j)
        acc[i][j] = __builtin_amdgcn_mfma_f32_16x16x32_bf16(af[i], wf[j], acc[i][j], 0, 0, 0);
  }
  // epilogue (per wave: 64x64 at m0w, n0w)
  const int m0w = m0 + (wid >> 1) * 64;
  const int n0w = n0 + (wid & 1) * 64;
  const int rbase = m0w + (lane >> 4) * 4;
#pragma unroll
  for (int i = 0; i < 4; ++i) {
#pragma unroll
    for (int j = 0; j < 4; ++j) {
      int col = n0w + j * 16 + fr;
      if (col < g.N) {
#pragma unroll
        for (int r = 0; r < 4; ++r) {
          int row = rbase + i * 16 + r;
          float v = acc[i][j][r] * g.alpha;
          if (g.bias) v += g.bias[col];
          if (g.add) v += g.add[(size_t)row * g.ldad + col];
          if (g.act == 1) v = fmaxf(v, 0.f);
          else if (g.act == 2) v = (v > 20.f) ? v : log1pf(expf(v));
          if (g.Cf) {
            if (g.ct) g.Cf[(size_t)col * g.ldcf + row] = v;
            else      g.Cf[(size_t)row * g.ldcf + col] = v;
          }
          if (g.Cb) g.Cb[(size_t)row * g.ldcb + col] = (__bf16)v;
        }
      }
    }
  }
}

static void launch_gemm128(hipStream_t st,
    const __bf16* A, int lda, const __bf16* W, int ldw,
    const float* bias, const float* add, int ldad,
    float* Cf, int ldcf, __bf16* Cb, int ldcb,
    int M, int N, int K, float alpha, int act, int ct = 0) {
  Gemm128Args g;
  g.A = A; g.W = W; g.bias = bias; g.add = add; g.Cf = Cf; g.Cb = Cb;
  g.lda = lda; g.ldw = ldw; g.ldad = ldad; g.ldcf = ldcf; g.ldcb = ldcb;
  g.M = M; g.N = N; g.K = K; g.alpha = alpha; g.act = act; g.ct = ct;
  dim3 grid(M / 128, (N + 127) / 128);
  gemm128_kernel<<<grid, 256, 0, st>>>(g);
}

// ---------------- V transpose: qkv[b][l][2D + h*64 + d] -> vt[bh][d][l] ----------------
__global__ __launch_bounds__(256) void transpose_v_kernel(const __bf16* __restrict__ qkv,
                                                          __bf16* __restrict__ vt) {
  int bh = blockIdx.x, b = bh >> 3, h = bh & 7;
  const __bf16* s = qkv + (size_t)b * 512 * 1536 + 1024 + h * 64;
  __bf16* dst = vt + (size_t)bh * 64 * 512;
  __shared__ __align__(16) __bf16 tile[64 * 72];
  int tid = threadIdx.x;
  for (int l0 = 0; l0 < 512; l0 += 64) {
    __syncthreads();
#pragma unroll
    for (int it = 0; it < 2; ++it) {
      int idx = tid + it * 256;
      int l = idx >> 3, dc = (idx & 7) * 8;
      *(uint4*)&tile[l * 72 + dc] = *(const uint4*)(s + (size_t)(l0 + l) * 1536 + dc);
    }
    __syncthreads();
#pragma unroll
    for (int it = 0; it < 2; ++it) {
      int idx = tid + it * 256;
      int dd = idx >> 3, lc = (idx & 7) * 8;
      __align__(16) __bf16 tmp[8];
#pragma unroll
      for (int j = 0; j < 8; ++j) tmp[j] = tile[(lc + j) * 72 + dd];
      *(uint4*)(dst + (size_t)dd * 512 + l0 + lc) = *(uint4*)tmp;
    }
  }
}

// ---------------- row softmax over 512 cols, fp32 in -> bf16 out ----------------
__global__ __launch_bounds__(256) void softmax_kernel(const float* __restrict__ S,
                                                      __bf16* __restrict__ P) {
  int row = blockIdx.x * 4 + (threadIdx.x >> 6);
  int lane = threadIdx.x & 63;
  const float* sp = S + (size_t)row * 512 + lane * 8;
  float v[8];
  *(float4*)(v) = *(const float4*)(sp);
  *(float4*)(v + 4) = *(const float4*)(sp + 4);
  float m = v[0];
#pragma unroll
  for (int k = 1; k < 8; ++k) m = fmaxf(m, v[k]);
  m = wave_max(m);
  float s = 0.f;
#pragma unroll
  for (int k = 0; k < 8; ++k) { v[k] = __expf(v[k] - m); s += v[k]; }
  s = wave_sum(s);
  float inv = 1.f / s;
  bf16x8 r;
#pragma unroll
  for (int k = 0; k < 8; ++k) r[k] = (__bf16)(v[k] * inv);
  *(bf16x8*)(P + (size_t)row * 512 + lane * 8) = r;
}

// ---------------- depthwise causal conv (DC=4) + silu, TRANSPOSED fp32 outputs ----------------
__global__ __launch_bounds__(256) void conv_silu_t_kernel(
    const float* __restrict__ xz, const float* __restrict__ cw, const float* __restrict__ cb,
    __bf16* __restrict__ xcb, float* __restrict__ uT, float* __restrict__ s1T) {
  int c0 = blockIdx.x * 64, t0 = blockIdx.y * 64, b = blockIdx.z;
  __shared__ float su[64][65];
  __shared__ float sz[64][65];
  int c = threadIdx.x & 63;
  int tr = threadIdx.x >> 6;  // 0..3
  int ch = c0 + c;
  float w0 = cw[ch * 4 + 0], w1 = cw[ch * 4 + 1], w2 = cw[ch * 4 + 2], w3 = cw[ch * 4 + 3];
  float bias = cb[ch];
#pragma unroll 4
  for (int it = 0; it < 16; ++it) {
    int tt = it * 4 + tr;
    int t = t0 + tt;
    const float* col = xz + (size_t)b * 512 * 2048 + ch;
    float acc = bias;
    if (t >= 3) {
      acc = fmaf(w0, col[(size_t)(t - 3) * 2048], acc);
      acc = fmaf(w1, col[(size_t)(t - 2) * 2048], acc);
      acc = fmaf(w2, col[(size_t)(t - 1) * 2048], acc);
    } else {
      if (t - 3 >= 0) acc = fmaf(w0, col[(size_t)(t - 3) * 2048], acc);
      if (t - 2 >= 0) acc = fmaf(w1, col[(size_t)(t - 2) * 2048], acc);
      if (t - 1 >= 0) acc = fmaf(w2, col[(size_t)(t - 1) * 2048], acc);
    }
    acc = fmaf(w3, col[(size_t)t * 2048], acc);
    float u = acc / (1.f + __expf(-acc));
    su[tt][c] = u;
    xcb[(size_t)(b * 512 + t) * 1024 + ch] = (__bf16)u;
    float zv = col[(size_t)t * 2048 + 1024];
    sz[tt][c] = zv / (1.f + __expf(-zv));
  }
  __syncthreads();
  int c2 = threadIdx.x >> 2;
  int tb = (threadIdx.x & 3) * 16;
  size_t g = (size_t)(c0 + c2) * 2048 + (size_t)b * 512 + t0 + tb;
#pragma unroll
  for (int i = 0; i < 16; ++i) {
    uT[g + i] = su[tb + i][c2];
    s1T[g + i] = sz[tb + i][c2];
  }
}

// ---------------- chunked selective scan ----------------
// Phase 1: h from h0=0, emit per-lane chunk summary (Aprod = exp2(aL2*sum dt), h_end).
__global__ __launch_bounds__(256) void scan_p1_kernel(
    const float* __restrict__ dtT, const float* __restrict__ uT,
    const float* __restrict__ xdbl, const float* __restrict__ A_log,
    float* __restrict__ Aprod, float* __restrict__ hend) {
  int w = (blockIdx.x * 256 + threadIdx.x) >> 6;  // 0..32767 = (b*1024+di)*8+c
  int lane = threadIdx.x & 63;
  int c = w & 7, di = (w >> 3) & 1023, b = w >> 13;
  float aL2 = -__expf(A_log[di * 64 + lane]) * 1.4426950408889634f;  // A*log2(e)
  int t0 = c * 64;
  size_t sbase = (size_t)di * 2048 + (size_t)b * 512 + t0;
  const float* dtp = dtT + sbase;
  const float* up = uT + sbase;
  const float* bp = xdbl + ((size_t)(b * 512 + t0)) * 160 + 32 + lane;
  float h = 0.f, sdt = 0.f;
#pragma unroll 8
  for (int s = 0; s < 64; ++s) {
    float dtv = dtp[s];
    float duv = dtv * up[s];
    float Bv = bp[(size_t)s * 160];
    float dec = exp2f(dtv * aL2);
    sdt += dtv;
    h = fmaf(dec, h, duv * Bv);
  }
  size_t o = (size_t)w * 64 + lane;
  Aprod[o] = exp2f(sdt * aL2);
  hend[o] = h;
}

// Phase 2: compose 8 chunk summaries per (b,di) -> h_start per chunk.
__global__ __launch_bounds__(256) void scan_p2_kernel(
    const float* __restrict__ Aprod, const float* __restrict__ hend,
    float* __restrict__ hstart) {
  int w = (blockIdx.x * 256 + threadIdx.x) >> 6;  // 0..4095 = b*1024+di
  int lane = threadIdx.x & 63;
  float h = 0.f;
  size_t base = (size_t)w * 8 * 64 + lane;
#pragma unroll
  for (int c = 0; c < 8; ++c) {
    size_t o = base + (size_t)c * 64;
    hstart[o] = h;
    h = fmaf(Aprod[o], h, hend[o]);
  }
}

// Phase 3: two-section LDS row-sum. Steps 0..31 fill Q rows 0..31 (row s complete at
// step s since all 64 lanes write it) -> lanes 0..31 reduce their own row; steps 32..63
// reuse the 32-row buffer -> lanes 32..63 reduce. Per-wave buffer, in-order DS pipe:
// no __syncthreads needed. LDS 8.3KB/wave -> ~18 waves/CU occupancy.
__global__ __launch_bounds__(128) void scan_p3_kernel(
    const float* __restrict__ dtT, const float* __restrict__ uT,
    const float* __restrict__ s1T, const float* __restrict__ xdbl,
    const float* __restrict__ A_log, const float* __restrict__ Dskip,
    const float* __restrict__ hstart, __bf16* __restrict__ yT) {
  __shared__ float Q[2][32][65];  // 16640 B per 128-thread block
  int wl = threadIdx.x >> 6;
  int w = (blockIdx.x * 128 + threadIdx.x) >> 6;
  int lane = threadIdx.x & 63;
  int c = w & 7, di = (w >> 3) & 1023, b = w >> 13;
  float aL2 = -__expf(A_log[di * 64 + lane]) * 1.4426950408889634f;
  int t0 = c * 64;
  size_t sbase = (size_t)di * 2048 + (size_t)b * 512 + t0;
  const float* dtp = dtT + sbase;
  const float* up = uT + sbase;
  const float* bp = xdbl + ((size_t)(b * 512 + t0)) * 160 + 32 + lane;
  const float* cp = bp + 64;
  float h = hstart[(size_t)w * 64 + lane];
  float y = 0.f;
#pragma unroll 8
  for (int s = 0; s < 32; ++s) {
    float dtv = dtp[s];
    float duv = dtv * up[s];
    float Bv = bp[(size_t)s * 160];
    float Cv = cp[(size_t)s * 160];
    float dec = exp2f(dtv * aL2);
    h = fmaf(dec, h, duv * Bv);
    Q[wl][s][lane] = h * Cv;
  }
  if (lane < 32) {
    const float* row = &Q[wl][lane][0];
    float a0 = 0.f, a1 = 0.f, a2 = 0.f, a3 = 0.f;
#pragma unroll
    for (int k = 0; k < 64; k += 4) {
      a0 += row[k]; a1 += row[k + 1]; a2 += row[k + 2]; a3 += row[k + 3];
    }
    y = (a0 + a1) + (a2 + a3);
  }
#pragma unroll 8
  for (int s = 32; s < 64; ++s) {
    float dtv = dtp[s];
    float duv = dtv * up[s];
    float Bv = bp[(size_t)s * 160];
    float Cv = cp[(size_t)s * 160];
    float dec = exp2f(dtv * aL2);
    h = fmaf(dec, h, duv * Bv);
    Q[wl][s - 32][lane] = h * Cv;
  }
  if (lane >= 32) {
    const float* row = &Q[wl][lane - 32][0];
    float a0 = 0.f, a1 = 0.f, a2 = 0.f, a3 = 0.f;
#pragma unroll
    for (int k = 0; k < 64; k += 4) {
      a0 += row[k]; a1 += row[k + 1]; a2 += row[k + 2]; a3 += row[k + 3];
    }
    y = (a0 + a1) + (a2 + a3);
  }
  float ue = up[lane];
  float s1e = s1T[sbase + lane];
  yT[sbase + lane] = (__bf16)((y + ue * Dskip[di]) * s1e);
}

// ---------------- yT [1024][2048] -> yb [2048][1024] bf16 transpose ----------------
__global__ __launch_bounds__(256) void transpose_y_kernel(const __bf16* __restrict__ src,
                                                          __bf16* __restrict__ dst) {
  int r0 = blockIdx.x * 64;   // di
  int c0 = blockIdx.y * 64;   // b*512+t
  __shared__ __align__(16) __bf16 tile[64 * 72];
  int tid = threadIdx.x;
#pragma unroll
  for (int it = 0; it < 2; ++it) {
    int idx = tid + it * 256;
    int r = idx >> 3, cc = (idx & 7) * 8;
    *(uint4*)&tile[r * 72 + cc] = *(const uint4*)(src + (size_t)(r0 + r) * 2048 + c0 + cc);
  }
  __syncthreads();
#pragma unroll
  for (int it = 0; it < 2; ++it) {
    int idx = tid + it * 256;
    int cr = idx >> 3, rc = (idx & 7) * 8;
    __align__(16) __bf16 tmp[8];
#pragma unroll
    for (int j = 0; j < 8; ++j) tmp[j] = tile[(rc + j) * 72 + cr];
    *(uint4*)(dst + (size_t)(c0 + cr) * 1024 + r0 + rc) = *(uint4*)tmp;
  }
}

// ---------------- layernorm over D=512, writes fp32 and/or bf16 ----------------
__global__ __launch_bounds__(256) void layernorm_kernel(const float* __restrict__ in,
    const float* __restrict__ g, const float* __restrict__ b,
    float* __restrict__ outf, __bf16* __restrict__ outb) {
  int row = blockIdx.x * 4 + (threadIdx.x >> 6);
  int lane = threadIdx.x & 63;
  const float* p = in + (size_t)row * 512 + lane * 8;
  float v[8];
  *(float4*)(v) = *(const float4*)(p);
  *(float4*)(v + 4) = *(const float4*)(p + 4);
  float s = 0.f;
#pragma unroll
  for (int k = 0; k < 8; ++k) s += v[k];
  float mean = wave_sum(s) * (1.f / 512.f);
  float q = 0.f;
#pragma unroll
  for (int k = 0; k < 8; ++k) { float d = v[k] - mean; q += d * d; }
  float var = wave_sum(q) * (1.f / 512.f);
  float rs = rsqrtf(var + 1e-5f);
  float gv[8], bv[8];
  *(float4*)(gv) = *(const float4*)(g + lane * 8);
  *(float4*)(gv + 4) = *(const float4*)(g + lane * 8 + 4);
  *(float4*)(bv) = *(const float4*)(b + lane * 8);
  *(float4*)(bv + 4) = *(const float4*)(b + lane * 8 + 4);
  float o[8];
#pragma unroll
  for (int k = 0; k < 8; ++k) o[k] = (v[k] - mean) * rs * gv[k] + bv[k];
  if (outf) {
    float* op = outf + (size_t)row * 512 + lane * 8;
    *(float4*)(op) = *(const float4*)(o);
    *(float4*)(op + 4) = *(const float4*)(o + 4);
  }
  if (outb) {
    bf16x8 r;
#pragma unroll
    for (int k = 0; k < 8; ++k) r[k] = (__bf16)o[k];
    *(bf16x8*)(outb + (size_t)row * 512 + lane * 8) = r;
  }
}

// =====================================================================================
extern "C" void kernel_launch(void* const* d_in, const int* in_sizes, int n_in,
                              void* d_out, int out_size, void* d_ws, size_t ws_size,
                              hipStream_t stream) {
  const float* src    = (const float*)d_in[0];
  const float* w_qkv  = (const float*)d_in[1];
  const float* b_qkv  = (const float*)d_in[2];
  const float* w_o    = (const float*)d_in[3];
  const float* b_o    = (const float*)d_in[4];
  const float* w1     = (const float*)d_in[5];
  const float* b1     = (const float*)d_in[6];
  const float* w2     = (const float*)d_in[7];
  const float* b2     = (const float*)d_in[8];
  const float* n1g    = (const float*)d_in[9];
  const float* n1b    = (const float*)d_in[10];
  const float* w_in   = (const float*)d_in[11];
  const float* conv_w = (const float*)d_in[12];
  const float* conv_b = (const float*)d_in[13];
  const float* w_xp   = (const float*)d_in[14];
  const float* w_dt   = (const float*)d_in[15];
  const float* b_dt   = (const float*)d_in[16];
  const float* A_log  = (const float*)d_in[17];
  const float* D_skip = (const float*)d_in[18];
  const float* w_out  = (const float*)d_in[19];
  const float* nfg    = (const float*)d_in[20];
  const float* nfb    = (const float*)d_in[21];
  (void)in_sizes; (void)n_in; (void)out_size; (void)ws_size;

  char* ws = (char*)d_ws;
  // bf16 weights (all layers)
  __bf16* Wqkv = (__bf16*)(ws + 0);          // 4*1536*512
  __bf16* Wo   = (__bf16*)(ws + 6291456);    // 4*512*512
  __bf16* W1   = (__bf16*)(ws + 8388608);    // 4*2048*512
  __bf16* W2   = (__bf16*)(ws + 16777216);   // 4*512*2048
  __bf16* Win  = (__bf16*)(ws + 25165824);   // 4*2048*512
  __bf16* Wxp  = (__bf16*)(ws + 33554432);   // 4*160*1024
  __bf16* Wdt  = (__bf16*)(ws + 34865152);   // 4*1024*32
  __bf16* Wout = (__bf16*)(ws + 35127296);   // 4*512*1024
  // activations
  __bf16* xb16 = (__bf16*)(ws + 39321600);   // 2048*512
  float*  xf32 = (float*)(ws + 41418752);    // 2048*512
  __bf16* qkvb = (__bf16*)(ws + 45613056);   // 2048*1536 (dead after PV gemm)
  __bf16* vt   = (__bf16*)(ws + 51904512);   // 32*64*512 (dead after PV gemm)
  __bf16* o_b  = (__bf16*)(ws + 54001664);   // 2048*512  (dead after Wo gemm)
  float*  a_f  = (float*)(ws + 56098816);    // 2048*512  (live until out_proj epilogue)
  __bf16* hb   = (__bf16*)(ws + 60293120);   // 2048*512
  float*  h2   = (float*)(ws + 62390272);    // 2048*512 fp32
  // region R1 (32MB, disjoint lifetimes)
  float*  Sf    = (float*)(ws + 66584576);
  float*  xzf   = (float*)(ws + 66584576);
  float*  dtT   = (float*)(ws + 66584576);
  float*  hend0 = (float*)(ws + 74973184);
  float*  uT    = (float*)(ws + 83361792);
  float*  s1T   = (float*)(ws + 91750400);
  // scan summaries overlaying dead regions during scan phases:
  float*  hstart = (float*)(ws + 45613056);  // over qkvb+vt (8MB), dead after PV
  __bf16* yT     = (__bf16*)(ws + 60293120); // over hb+h2[0:2MB] (4MB), dead during scan
  // region R2: P bf16 (16MB) | { xcb b16, xdbl f32/b16, y b16, ffn-mid b16 }
  __bf16* Pb    = (__bf16*)(ws + 100139008); // 32*512*512
  __bf16* xcb   = (__bf16*)(ws + 100139008);               // 2048*1024 bf16
  float*  xdblf = (float*)(ws + 100139008 + 4194304);      // 2048*160
  __bf16* xdblb = (__bf16*)(ws + 100139008 + 5505024);     // 2048*160
  __bf16* yb    = (__bf16*)(ws + 100139008 + 6160384);     // 2048*1024
  __bf16* fb    = (__bf16*)(ws + 100139008 + 10354688);    // 2048*2048 (dead during scan)
  float*  Aprod = (float*)(ws + 110493696);  // over fb (8MB exactly)
  // total = 118882304 bytes (~113.4 MB) -- unchanged

  auto cvt = [&](const float* s, __bf16* dptr, long long n) {
    int n4 = (int)(n / 4);
    cvt_kernel<<<(n4 + 255) / 256, 256, 0, stream>>>(s, dptr, n4);
  };
  cvt(w_qkv, Wqkv, 4LL * 1536 * 512);
  cvt(w_o,   Wo,   4LL * 512 * 512);
  cvt(w1,    W1,   4LL * 2048 * 512);
  cvt(w2,    W2,   4LL * 512 * 2048);
  cvt(w_in,  Win,  4LL * 2048 * 512);
  cvt(w_xp,  Wxp,  4LL * 160 * 1024);
  cvt(w_dt,  Wdt,  4LL * 1024 * 32);
  cvt(w_out, Wout, 4LL * 512 * 1024);

  pe_kernel<<<4096, 256, 0, stream>>>(src, xb16);

  for (int i = 0; i < 4; ++i) {
    // ---- attention branch ----
    launch_gemm128(stream, xb16, 512, Wqkv + (size_t)i * 1536 * 512, 512,
                   b_qkv + i * 1536, nullptr, 0,
                   nullptr, 0, qkvb, 1536, 2048, 1536, 512, 1.f, 0);
    transpose_v_kernel<<<32, 256, 0, stream>>>(qkvb, vt);
    launch_gemm(stream, qkvb, 1536, 512LL * 1536, 64, qkvb + 512, 1536, 512LL * 1536, 64,
                nullptr, nullptr, 0, 0, 0,
                Sf, 512, 2097152LL, 262144LL, nullptr, 0, 0, 0,
                512, 512, 64, 32, 8, 0.125f, 0);
    softmax_kernel<<<4096, 256, 0, stream>>>(Sf, Pb);
    launch_gemm(stream, Pb, 512, 2097152LL, 262144LL, vt, 512, 262144LL, 32768LL,
                nullptr, nullptr, 0, 0, 0,
                nullptr, 0, 0, 0, o_b, 512, 262144LL, 64LL,
                512, 64, 512, 32, 8, 1.f, 0);
    launch_gemm128(stream, o_b, 512, Wo + (size_t)i * 512 * 512, 512,
                   b_o + i * 512, nullptr, 0,
                   a_f, 512, nullptr, 0, 2048, 512, 512, 1.f, 0);
    // ---- mamba branch ----
    launch_gemm128(stream, xb16, 512, Win + (size_t)i * 2048 * 512, 512,
                   nullptr, nullptr, 0,
                   xzf, 2048, nullptr, 0, 2048, 2048, 512, 1.f, 0);
    conv_silu_t_kernel<<<dim3(16, 8, 4), 256, 0, stream>>>(
        xzf, conv_w + i * 1024 * 4, conv_b + i * 1024, xcb, uT, s1T);
    launch_gemm128(stream, xcb, 1024, Wxp + (size_t)i * 160 * 1024, 1024,
                   nullptr, nullptr, 0,
                   xdblf, 160, xdblb, 160, 2048, 160, 1024, 1.f, 0);
    // dt = softplus(dt_in @ Wdt^T + b_dt) -> TRANSPOSED into dtT[di][b*512+t]
    launch_gemm128(stream, xdblb, 160, Wdt + (size_t)i * 1024 * 32, 32,
                   b_dt + i * 1024, nullptr, 0,
                   dtT, 2048, nullptr, 0, 2048, 1024, 32, 1.f, 2, /*ct=*/1);
    // chunked scan: 3 phases + transpose
    scan_p1_kernel<<<8192, 256, 0, stream>>>(dtT, uT, xdblf,
                                             A_log + (size_t)i * 1024 * 64, Aprod, hend0);
    scan_p2_kernel<<<1024, 256, 0, stream>>>(Aprod, hend0, hstart);
    scan_p3_kernel<<<16384, 128, 0, stream>>>(dtT, uT, s1T, xdblf,
                                              A_log + (size_t)i * 1024 * 64,
                                              D_skip + i * 1024, hstart, yT);
    transpose_y_kernel<<<dim3(16, 32), 256, 0, stream>>>(yT, yb);
    launch_gemm128(stream, yb, 1024, Wout + (size_t)i * 512 * 1024, 1024,
                   nullptr, a_f, 512,
                   nullptr, 0, hb, 512, 2048, 512, 1024, 1.f, 0);
    // ---- FFN + LN ----
    launch_gemm128(stream, hb, 512, W1 + (size_t)i * 2048 * 512, 512,
                   b1 + i * 2048, nullptr, 0,
                   nullptr, 0, fb, 2048, 2048, 2048, 512, 1.f, 1);
    launch_gemm128(stream, fb, 2048, W2 + (size_t)i * 512 * 2048, 2048,
                   b2 + i * 512, nullptr, 0,
                   h2, 512, nullptr, 0, 2048, 512, 2048, 1.f, 0);
    layernorm_kernel<<<512, 256, 0, stream>>>(h2, n1g + i * 512, n1b + i * 512, xf32, xb16);
  }
  // final layernorm -> d_out (fp32)
  layernorm_kernel<<<512, 256, 0, stream>>>(xf32, nfg, nfb, (float*)d_out, nullptr);
}

// Round 6
// 1718.692 us; speedup vs baseline: 1.3961x; 1.3961x over previous
//
#include <hip/hip_runtime.h>
#include <cmath>

// Mamba_TransformerEncoder on MI355X (gfx950).
// B=4, L=512, D=512, NH=8, FF=2048, NL=4, DI=1024, DS=64, DC=4, DTR=32.
// R6: gemm_sk_kernel -- 64x64 tile, 4 waves splitting K into 4 slices (direct-global
// fragment loads), deterministic LDS tree-reduce, 256-thread epilogue. Fixes R5's
// occupancy collapse (128^2 tiles -> 64-block grids). S-gemm (K=64) and dt-gemm (K=32,
// transposed out) remain on the single-wave gemm_kernel. Scan pipeline as R5.

typedef __attribute__((ext_vector_type(8))) __bf16 bf16x8;
typedef __attribute__((ext_vector_type(4))) __bf16 bf16x4;
typedef __attribute__((ext_vector_type(4))) float f32x4;

#define DEV static __device__ __forceinline__

DEV float wave_sum(float x) {
#pragma unroll
  for (int o = 32; o; o >>= 1) x += __shfl_xor(x, o, 64);
  return x;
}
DEV float wave_max(float x) {
#pragma unroll
  for (int o = 32; o; o >>= 1) x = fmaxf(x, __shfl_xor(x, o, 64));
  return x;
}

// ---------------- fp32 -> bf16 convert (x4 vectorized) ----------------
__global__ void cvt_kernel(const float* __restrict__ s, __bf16* __restrict__ d, int n4) {
  int i = blockIdx.x * 256 + threadIdx.x;
  if (i < n4) {
    float4 v = ((const float4*)s)[i];
    bf16x4 r = {(__bf16)v.x, (__bf16)v.y, (__bf16)v.z, (__bf16)v.w};
    *(bf16x4*)(d + (size_t)i * 4) = r;
  }
}

// ---------------- positional encoding + bf16 cast ----------------
__global__ void pe_kernel(const float* __restrict__ src, __bf16* __restrict__ xb) {
  int idx = blockIdx.x * 256 + threadIdx.x;  // B*L*D = 1048576
  int d = idx & 511;
  int l = (idx >> 9) & 511;
  float ang = (float)l * expf((float)(d & ~1) * (-9.210340371976184f / 512.f));
  float pe = (d & 1) ? cosf(ang) : sinf(ang);
  xb[idx] = (__bf16)(src[idx] + pe);
}

// ============ single-wave 64x64 GEMM (batched attention S; dt-gemm w/ ct) ============
struct GemmArgs {
  const __bf16* A; const __bf16* W;
  const float* bias; const float* add;
  float* Cf; __bf16* Cb;
  long long sAzb, sAzh, sWzb, sWzh, sADzb, sADzh, sCfzb, sCfzh, sCbzb, sCbzh;
  int lda, ldw, ldad, ldcf, ldcb;
  int M, N, K, ZH;
  float alpha; int act;  // 0 none, 1 relu, 2 softplus
  int ct;
};

__global__ __launch_bounds__(64) void gemm_kernel(GemmArgs g) {
  const int lane = threadIdx.x;
  const int m0 = blockIdx.x * 64, n0 = blockIdx.y * 64;
  const int zb = blockIdx.z / g.ZH, zh = blockIdx.z % g.ZH;
  const __bf16* A = g.A + zb * g.sAzb + zh * g.sAzh;
  const __bf16* W = g.W + zb * g.sWzb + zh * g.sWzh;
  const int fr = lane & 15;
  const int fk = (lane >> 4) * 8;
  const __bf16* pa[4]; const __bf16* pw[4];
#pragma unroll
  for (int i = 0; i < 4; ++i) {
    int ra = m0 + i * 16 + fr;
    pa[i] = A + (size_t)ra * g.lda + fk;
    int rw = n0 + i * 16 + fr; if (rw > g.N - 1) rw = g.N - 1;
    pw[i] = W + (size_t)rw * g.ldw + fk;
  }
  f32x4 acc[4][4] = {};
  for (int k0 = 0; k0 < g.K; k0 += 32) {
    bf16x8 af[4], wf[4];
#pragma unroll
    for (int i = 0; i < 4; ++i) af[i] = *(const bf16x8*)(pa[i] + k0);
#pragma unroll
    for (int j = 0; j < 4; ++j) wf[j] = *(const bf16x8*)(pw[j] + k0);
#pragma unroll
    for (int i = 0; i < 4; ++i)
#pragma unroll
      for (int j = 0; j < 4; ++j)
        acc[i][j] = __builtin_amdgcn_mfma_f32_16x16x32_bf16(af[i], wf[j], acc[i][j], 0, 0, 0);
  }
  const float* addp = g.add ? g.add + zb * g.sADzb + zh * g.sADzh : nullptr;
  float* cf = g.Cf ? g.Cf + zb * g.sCfzb + zh * g.sCfzh : nullptr;
  __bf16* cb = g.Cb ? g.Cb + zb * g.sCbzb + zh * g.sCbzh : nullptr;
  const int rbase = m0 + (lane >> 4) * 4;
#pragma unroll
  for (int i = 0; i < 4; ++i) {
#pragma unroll
    for (int j = 0; j < 4; ++j) {
      int col = n0 + j * 16 + fr;
      if (col < g.N) {
#pragma unroll
        for (int r = 0; r < 4; ++r) {
          int row = rbase + i * 16 + r;
          float v = acc[i][j][r] * g.alpha;
          if (g.bias) v += g.bias[col];
          if (addp) v += addp[(size_t)row * g.ldad + col];
          if (g.act == 1) v = fmaxf(v, 0.f);
          else if (g.act == 2) v = (v > 20.f) ? v : log1pf(expf(v));
          if (cf) {
            if (g.ct) cf[(size_t)col * g.ldcf + row] = v;
            else      cf[(size_t)row * g.ldcf + col] = v;
          }
          if (cb) cb[(size_t)row * g.ldcb + col] = (__bf16)v;
        }
      }
    }
  }
}

static void launch_gemm(hipStream_t st,
    const __bf16* A, int lda, long long sAzb, long long sAzh,
    const __bf16* W, int ldw, long long sWzb, long long sWzh,
    const float* bias,
    const float* add, int ldad, long long sADzb, long long sADzh,
    float* Cf, int ldcf, long long sCfzb, long long sCfzh,
    __bf16* Cb, int ldcb, long long sCbzb, long long sCbzh,
    int M, int N, int K, int Z, int ZH, float alpha, int act, int ct = 0) {
  GemmArgs g;
  g.A = A; g.W = W; g.bias = bias; g.add = add; g.Cf = Cf; g.Cb = Cb;
  g.sAzb = sAzb; g.sAzh = sAzh; g.sWzb = sWzb; g.sWzh = sWzh;
  g.sADzb = sADzb; g.sADzh = sADzh; g.sCfzb = sCfzb; g.sCfzh = sCfzh;
  g.sCbzb = sCbzb; g.sCbzh = sCbzh;
  g.lda = lda; g.ldw = ldw; g.ldad = ldad; g.ldcf = ldcf; g.ldcb = ldcb;
  g.M = M; g.N = N; g.K = K; g.ZH = ZH; g.alpha = alpha; g.act = act; g.ct = ct;
  dim3 grid(M / 64, (N + 63) / 64, Z);
  gemm_kernel<<<grid, 64, 0, st>>>(g);
}

// ============ split-K 4-wave 64x64 GEMM ============
// Wave w computes the 64x64 tile over K-slice [w*K/4,(w+1)*K/4) with direct-global
// fragment loads; deterministic LDS tree-reduce (w0+w1)+(w2+w3); 256-thread epilogue.
// Row stride 66 in the reduce buffers -> 2-way bank aliasing only (free).
// Requires K % 128 == 0, M % 64 == 0. No ct support (dt-gemm stays on gemm_kernel).
__global__ __launch_bounds__(256) void gemm_sk_kernel(GemmArgs g) {
  __shared__ float red[2][64 * 66];  // 33792 B
  const int tid = threadIdx.x;
  const int lane = tid & 63;
  const int wid = tid >> 6;
  const int m0 = blockIdx.x * 64, n0 = blockIdx.y * 64;
  const int zb = blockIdx.z / g.ZH, zh = blockIdx.z % g.ZH;
  const __bf16* A = g.A + zb * g.sAzb + zh * g.sAzh;
  const __bf16* W = g.W + zb * g.sWzb + zh * g.sWzh;
  const int fr = lane & 15;
  const int fk = (lane >> 4) * 8;
  const int kbase = wid * (g.K >> 2);
  const __bf16* pa[4]; const __bf16* pw[4];
#pragma unroll
  for (int i = 0; i < 4; ++i) {
    int ra = m0 + i * 16 + fr;
    pa[i] = A + (size_t)ra * g.lda + kbase + fk;
    int rw = n0 + i * 16 + fr; if (rw > g.N - 1) rw = g.N - 1;
    pw[i] = W + (size_t)rw * g.ldw + kbase + fk;
  }
  f32x4 acc[4][4] = {};
  const int kend = g.K >> 2;
  for (int k0 = 0; k0 < kend; k0 += 32) {
    bf16x8 af[4], wf[4];
#pragma unroll
    for (int i = 0; i < 4; ++i) af[i] = *(const bf16x8*)(pa[i] + k0);
#pragma unroll
    for (int j = 0; j < 4; ++j) wf[j] = *(const bf16x8*)(pw[j] + k0);
#pragma unroll
    for (int i = 0; i < 4; ++i)
#pragma unroll
      for (int j = 0; j < 4; ++j)
        acc[i][j] = __builtin_amdgcn_mfma_f32_16x16x32_bf16(af[i], wf[j], acc[i][j], 0, 0, 0);
  }
  // ---- LDS tree reduce: (w0 + w1) + (w2 + w3), deterministic ----
  float* buf0 = &red[0][0];
  float* buf1 = &red[1][0];
  auto store_acc = [&](float* buf) {
#pragma unroll
    for (int i = 0; i < 4; ++i)
#pragma unroll
      for (int j = 0; j < 4; ++j) {
        int rl = i * 16 + ((lane >> 4) << 2);
        int cl = j * 16 + fr;
#pragma unroll
        for (int r = 0; r < 4; ++r) buf[(rl + r) * 66 + cl] = acc[i][j][r];
      }
  };
  auto add_acc = [&](const float* buf) {
#pragma unroll
    for (int i = 0; i < 4; ++i)
#pragma unroll
      for (int j = 0; j < 4; ++j) {
        int rl = i * 16 + ((lane >> 4) << 2);
        int cl = j * 16 + fr;
#pragma unroll
        for (int r = 0; r < 4; ++r) acc[i][j][r] += buf[(rl + r) * 66 + cl];
      }
  };
  if (wid == 1) store_acc(buf0);
  if (wid == 3) store_acc(buf1);
  __syncthreads();
  if (wid == 0) add_acc(buf0);
  if (wid == 2) add_acc(buf1);
  __syncthreads();
  if (wid == 2) store_acc(buf0);
  __syncthreads();
  if (wid == 0) { add_acc(buf0); store_acc(buf0); }
  __syncthreads();
  // ---- epilogue: 256 threads x 16 elements ----
  const int rl = tid >> 2;
  const int c0l = (tid & 3) * 16;
  const int row = m0 + rl;
  const float* addp = g.add ? g.add + zb * g.sADzb + zh * g.sADzh : nullptr;
  float* cf = g.Cf ? g.Cf + zb * g.sCfzb + zh * g.sCfzh : nullptr;
  __bf16* cb = g.Cb ? g.Cb + zb * g.sCbzb + zh * g.sCbzh : nullptr;
  float v[16];
#pragma unroll
  for (int k = 0; k < 16; ++k) {
    float x = buf0[rl * 66 + c0l + k] * g.alpha;
    int col = n0 + c0l + k;
    if (col < g.N) {
      if (g.bias) x += g.bias[col];
      if (addp) x += addp[(size_t)row * g.ldad + col];
      if (g.act == 1) x = fmaxf(x, 0.f);
      else if (g.act == 2) x = (x > 20.f) ? x : log1pf(expf(x));
    }
    v[k] = x;
  }
  if (n0 + c0l + 15 < g.N) {  // fast vector path
    if (cf) {
      float* p = cf + (size_t)row * g.ldcf + n0 + c0l;
#pragma unroll
      for (int k = 0; k < 4; ++k) *(float4*)(p + k * 4) = *(float4*)(v + k * 4);
    }
    if (cb) {
      __bf16* p = cb + (size_t)row * g.ldcb + n0 + c0l;
#pragma unroll
      for (int h = 0; h < 2; ++h) {
        bf16x8 r;
#pragma unroll
        for (int k = 0; k < 8; ++k) r[k] = (__bf16)v[h * 8 + k];
        *(bf16x8*)(p + h * 8) = r;
      }
    }
  } else {
#pragma unroll
    for (int k = 0; k < 16; ++k) {
      int col = n0 + c0l + k;
      if (col < g.N) {
        if (cf) cf[(size_t)row * g.ldcf + col] = v[k];
        if (cb) cb[(size_t)row * g.ldcb + col] = (__bf16)v[k];
      }
    }
  }
}

static void launch_gemm_sk(hipStream_t st,
    const __bf16* A, int lda, long long sAzb, long long sAzh,
    const __bf16* W, int ldw, long long sWzb, long long sWzh,
    const float* bias,
    const float* add, int ldad, long long sADzb, long long sADzh,
    float* Cf, int ldcf, long long sCfzb, long long sCfzh,
    __bf16* Cb, int ldcb, long long sCbzb, long long sCbzh,
    int M, int N, int K, int Z, int ZH, float alpha, int act) {
  GemmArgs g;
  g.A = A; g.W = W; g.bias = bias; g.add = add; g.Cf = Cf; g.Cb = Cb;
  g.sAzb = sAzb; g.sAzh = sAzh; g.sWzb = sWzb; g.sWzh = sWzh;
  g.sADzb = sADzb; g.sADzh = sADzh; g.sCfzb = sCfzb; g.sCfzh = sCfzh;
  g.sCbzb = sCbzb; g.sCbzh = sCbzh;
  g.lda = lda; g.ldw = ldw; g.ldad = ldad; g.ldcf = ldcf; g.ldcb = ldcb;
  g.M = M; g.N = N; g.K = K; g.ZH = ZH; g.alpha = alpha; g.act = act; g.ct = 0;
  dim3 grid(M / 64, (N + 63) / 64, Z);
  gemm_sk_kernel<<<grid, 256, 0, st>>>(g);
}

// ---------------- V transpose: qkv[b][l][2D + h*64 + d] -> vt[bh][d][l] ----------------
__global__ __launch_bounds__(256) void transpose_v_kernel(const __bf16* __restrict__ qkv,
                                                          __bf16* __restrict__ vt) {
  int bh = blockIdx.x, b = bh >> 3, h = bh & 7;
  const __bf16* s = qkv + (size_t)b * 512 * 1536 + 1024 + h * 64;
  __bf16* dst = vt + (size_t)bh * 64 * 512;
  __shared__ __align__(16) __bf16 tile[64 * 72];
  int tid = threadIdx.x;
  for (int l0 = 0; l0 < 512; l0 += 64) {
    __syncthreads();
#pragma unroll
    for (int it = 0; it < 2; ++it) {
      int idx = tid + it * 256;
      int l = idx >> 3, dc = (idx & 7) * 8;
      *(uint4*)&tile[l * 72 + dc] = *(const uint4*)(s + (size_t)(l0 + l) * 1536 + dc);
    }
    __syncthreads();
#pragma unroll
    for (int it = 0; it < 2; ++it) {
      int idx = tid + it * 256;
      int dd = idx >> 3, lc = (idx & 7) * 8;
      __align__(16) __bf16 tmp[8];
#pragma unroll
      for (int j = 0; j < 8; ++j) tmp[j] = tile[(lc + j) * 72 + dd];
      *(uint4*)(dst + (size_t)dd * 512 + l0 + lc) = *(uint4*)tmp;
    }
  }
}

// ---------------- row softmax over 512 cols, fp32 in -> bf16 out ----------------
__global__ __launch_bounds__(256) void softmax_kernel(const float* __restrict__ S,
                                                      __bf16* __restrict__ P) {
  int row = blockIdx.x * 4 + (threadIdx.x >> 6);
  int lane = threadIdx.x & 63;
  const float* sp = S + (size_t)row * 512 + lane * 8;
  float v[8];
  *(float4*)(v) = *(const float4*)(sp);
  *(float4*)(v + 4) = *(const float4*)(sp + 4);
  float m = v[0];
#pragma unroll
  for (int k = 1; k < 8; ++k) m = fmaxf(m, v[k]);
  m = wave_max(m);
  float s = 0.f;
#pragma unroll
  for (int k = 0; k < 8; ++k) { v[k] = __expf(v[k] - m); s += v[k]; }
  s = wave_sum(s);
  float inv = 1.f / s;
  bf16x8 r;
#pragma unroll
  for (int k = 0; k < 8; ++k) r[k] = (__bf16)(v[k] * inv);
  *(bf16x8*)(P + (size_t)row * 512 + lane * 8) = r;
}

// ---------------- depthwise causal conv (DC=4) + silu, TRANSPOSED fp32 outputs ----------------
__global__ __launch_bounds__(256) void conv_silu_t_kernel(
    const float* __restrict__ xz, const float* __restrict__ cw, const float* __restrict__ cb,
    __bf16* __restrict__ xcb, float* __restrict__ uT, float* __restrict__ s1T) {
  int c0 = blockIdx.x * 64, t0 = blockIdx.y * 64, b = blockIdx.z;
  __shared__ float su[64][65];
  __shared__ float sz[64][65];
  int c = threadIdx.x & 63;
  int tr = threadIdx.x >> 6;  // 0..3
  int ch = c0 + c;
  float w0 = cw[ch * 4 + 0], w1 = cw[ch * 4 + 1], w2 = cw[ch * 4 + 2], w3 = cw[ch * 4 + 3];
  float bias = cb[ch];
#pragma unroll 4
  for (int it = 0; it < 16; ++it) {
    int tt = it * 4 + tr;
    int t = t0 + tt;
    const float* col = xz + (size_t)b * 512 * 2048 + ch;
    float acc = bias;
    if (t >= 3) {
      acc = fmaf(w0, col[(size_t)(t - 3) * 2048], acc);
      acc = fmaf(w1, col[(size_t)(t - 2) * 2048], acc);
      acc = fmaf(w2, col[(size_t)(t - 1) * 2048], acc);
    } else {
      if (t - 3 >= 0) acc = fmaf(w0, col[(size_t)(t - 3) * 2048], acc);
      if (t - 2 >= 0) acc = fmaf(w1, col[(size_t)(t - 2) * 2048], acc);
      if (t - 1 >= 0) acc = fmaf(w2, col[(size_t)(t - 1) * 2048], acc);
    }
    acc = fmaf(w3, col[(size_t)t * 2048], acc);
    float u = acc / (1.f + __expf(-acc));
    su[tt][c] = u;
    xcb[(size_t)(b * 512 + t) * 1024 + ch] = (__bf16)u;
    float zv = col[(size_t)t * 2048 + 1024];
    sz[tt][c] = zv / (1.f + __expf(-zv));
  }
  __syncthreads();
  int c2 = threadIdx.x >> 2;
  int tb = (threadIdx.x & 3) * 16;
  size_t g = (size_t)(c0 + c2) * 2048 + (size_t)b * 512 + t0 + tb;
#pragma unroll
  for (int i = 0; i < 16; ++i) {
    uT[g + i] = su[tb + i][c2];
    s1T[g + i] = sz[tb + i][c2];
  }
}

// ---------------- chunked selective scan ----------------
__global__ __launch_bounds__(256) void scan_p1_kernel(
    const float* __restrict__ dtT, const float* __restrict__ uT,
    const float* __restrict__ xdbl, const float* __restrict__ A_log,
    float* __restrict__ Aprod, float* __restrict__ hend) {
  int w = (blockIdx.x * 256 + threadIdx.x) >> 6;  // 0..32767 = (b*1024+di)*8+c
  int lane = threadIdx.x & 63;
  int c = w & 7, di = (w >> 3) & 1023, b = w >> 13;
  float aL2 = -__expf(A_log[di * 64 + lane]) * 1.4426950408889634f;  // A*log2(e)
  int t0 = c * 64;
  size_t sbase = (size_t)di * 2048 + (size_t)b * 512 + t0;
  const float* dtp = dtT + sbase;
  const float* up = uT + sbase;
  const float* bp = xdbl + ((size_t)(b * 512 + t0)) * 160 + 32 + lane;
  float h = 0.f, sdt = 0.f;
#pragma unroll 8
  for (int s = 0; s < 64; ++s) {
    float dtv = dtp[s];
    float duv = dtv * up[s];
    float Bv = bp[(size_t)s * 160];
    float dec = exp2f(dtv * aL2);
    sdt += dtv;
    h = fmaf(dec, h, duv * Bv);
  }
  size_t o = (size_t)w * 64 + lane;
  Aprod[o] = exp2f(sdt * aL2);
  hend[o] = h;
}

__global__ __launch_bounds__(256) void scan_p2_kernel(
    const float* __restrict__ Aprod, const float* __restrict__ hend,
    float* __restrict__ hstart) {
  int w = (blockIdx.x * 256 + threadIdx.x) >> 6;  // 0..4095 = b*1024+di
  int lane = threadIdx.x & 63;
  float h = 0.f;
  size_t base = (size_t)w * 8 * 64 + lane;
#pragma unroll
  for (int c = 0; c < 8; ++c) {
    size_t o = base + (size_t)c * 64;
    hstart[o] = h;
    h = fmaf(Aprod[o], h, hend[o]);
  }
}

// Phase 3: two-section LDS row-sum (R5 structure).
__global__ __launch_bounds__(128) void scan_p3_kernel(
    const float* __restrict__ dtT, const float* __restrict__ uT,
    const float* __restrict__ s1T, const float* __restrict__ xdbl,
    const float* __restrict__ A_log, const float* __restrict__ Dskip,
    const float* __restrict__ hstart, __bf16* __restrict__ yT) {
  __shared__ float Q[2][32][65];  // 16640 B per 128-thread block
  int wl = threadIdx.x >> 6;
  int w = (blockIdx.x * 128 + threadIdx.x) >> 6;
  int lane = threadIdx.x & 63;
  int c = w & 7, di = (w >> 3) & 1023, b = w >> 13;
  float aL2 = -__expf(A_log[di * 64 + lane]) * 1.4426950408889634f;
  int t0 = c * 64;
  size_t sbase = (size_t)di * 2048 + (size_t)b * 512 + t0;
  const float* dtp = dtT + sbase;
  const float* up = uT + sbase;
  const float* bp = xdbl + ((size_t)(b * 512 + t0)) * 160 + 32 + lane;
  const float* cp = bp + 64;
  float h = hstart[(size_t)w * 64 + lane];
  float y = 0.f;
#pragma unroll 8
  for (int s = 0; s < 32; ++s) {
    float dtv = dtp[s];
    float duv = dtv * up[s];
    float Bv = bp[(size_t)s * 160];
    float Cv = cp[(size_t)s * 160];
    float dec = exp2f(dtv * aL2);
    h = fmaf(dec, h, duv * Bv);
    Q[wl][s][lane] = h * Cv;
  }
  if (lane < 32) {
    const float* row = &Q[wl][lane][0];
    float a0 = 0.f, a1 = 0.f, a2 = 0.f, a3 = 0.f;
#pragma unroll
    for (int k = 0; k < 64; k += 4) {
      a0 += row[k]; a1 += row[k + 1]; a2 += row[k + 2]; a3 += row[k + 3];
    }
    y = (a0 + a1) + (a2 + a3);
  }
#pragma unroll 8
  for (int s = 32; s < 64; ++s) {
    float dtv = dtp[s];
    float duv = dtv * up[s];
    float Bv = bp[(size_t)s * 160];
    float Cv = cp[(size_t)s * 160];
    float dec = exp2f(dtv * aL2);
    h = fmaf(dec, h, duv * Bv);
    Q[wl][s - 32][lane] = h * Cv;
  }
  if (lane >= 32) {
    const float* row = &Q[wl][lane - 32][0];
    float a0 = 0.f, a1 = 0.f, a2 = 0.f, a3 = 0.f;
#pragma unroll
    for (int k = 0; k < 64; k += 4) {
      a0 += row[k]; a1 += row[k + 1]; a2 += row[k + 2]; a3 += row[k + 3];
    }
    y = (a0 + a1) + (a2 + a3);
  }
  float ue = up[lane];
  float s1e = s1T[sbase + lane];
  yT[sbase + lane] = (__bf16)((y + ue * Dskip[di]) * s1e);
}

// ---------------- yT [1024][2048] -> yb [2048][1024] bf16 transpose ----------------
__global__ __launch_bounds__(256) void transpose_y_kernel(const __bf16* __restrict__ src,
                                                          __bf16* __restrict__ dst) {
  int r0 = blockIdx.x * 64;   // di
  int c0 = blockIdx.y * 64;   // b*512+t
  __shared__ __align__(16) __bf16 tile[64 * 72];
  int tid = threadIdx.x;
#pragma unroll
  for (int it = 0; it < 2; ++it) {
    int idx = tid + it * 256;
    int r = idx >> 3, cc = (idx & 7) * 8;
    *(uint4*)&tile[r * 72 + cc] = *(const uint4*)(src + (size_t)(r0 + r) * 2048 + c0 + cc);
  }
  __syncthreads();
#pragma unroll
  for (int it = 0; it < 2; ++it) {
    int idx = tid + it * 256;
    int cr = idx >> 3, rc = (idx & 7) * 8;
    __align__(16) __bf16 tmp[8];
#pragma unroll
    for (int j = 0; j < 8; ++j) tmp[j] = tile[(rc + j) * 72 + cr];
    *(uint4*)(dst + (size_t)(c0 + cr) * 1024 + r0 + rc) = *(uint4*)tmp;
  }
}

// ---------------- layernorm over D=512, writes fp32 and/or bf16 ----------------
__global__ __launch_bounds__(256) void layernorm_kernel(const float* __restrict__ in,
    const float* __restrict__ g, const float* __restrict__ b,
    float* __restrict__ outf, __bf16* __restrict__ outb) {
  int row = blockIdx.x * 4 + (threadIdx.x >> 6);
  int lane = threadIdx.x & 63;
  const float* p = in + (size_t)row * 512 + lane * 8;
  float v[8];
  *(float4*)(v) = *(const float4*)(p);
  *(float4*)(v + 4) = *(const float4*)(p + 4);
  float s = 0.f;
#pragma unroll
  for (int k = 0; k < 8; ++k) s += v[k];
  float mean = wave_sum(s) * (1.f / 512.f);
  float q = 0.f;
#pragma unroll
  for (int k = 0; k < 8; ++k) { float d = v[k] - mean; q += d * d; }
  float var = wave_sum(q) * (1.f / 512.f);
  float rs = rsqrtf(var + 1e-5f);
  float gv[8], bv[8];
  *(float4*)(gv) = *(const float4*)(g + lane * 8);
  *(float4*)(gv + 4) = *(const float4*)(g + lane * 8 + 4);
  *(float4*)(bv) = *(const float4*)(b + lane * 8);
  *(float4*)(bv + 4) = *(const float4*)(b + lane * 8 + 4);
  float o[8];
#pragma unroll
  for (int k = 0; k < 8; ++k) o[k] = (v[k] - mean) * rs * gv[k] + bv[k];
  if (outf) {
    float* op = outf + (size_t)row * 512 + lane * 8;
    *(float4*)(op) = *(const float4*)(o);
    *(float4*)(op + 4) = *(const float4*)(o + 4);
  }
  if (outb) {
    bf16x8 r;
#pragma unroll
    for (int k = 0; k < 8; ++k) r[k] = (__bf16)o[k];
    *(bf16x8*)(outb + (size_t)row * 512 + lane * 8) = r;
  }
}

// =====================================================================================
extern "C" void kernel_launch(void* const* d_in, const int* in_sizes, int n_in,
                              void* d_out, int out_size, void* d_ws, size_t ws_size,
                              hipStream_t stream) {
  const float* src    = (const float*)d_in[0];
  const float* w_qkv  = (const float*)d_in[1];
  const float* b_qkv  = (const float*)d_in[2];
  const float* w_o    = (const float*)d_in[3];
  const float* b_o    = (const float*)d_in[4];
  const float* w1     = (const float*)d_in[5];
  const float* b1     = (const float*)d_in[6];
  const float* w2     = (const float*)d_in[7];
  const float* b2     = (const float*)d_in[8];
  const float* n1g    = (const float*)d_in[9];
  const float* n1b    = (const float*)d_in[10];
  const float* w_in   = (const float*)d_in[11];
  const float* conv_w = (const float*)d_in[12];
  const float* conv_b = (const float*)d_in[13];
  const float* w_xp   = (const float*)d_in[14];
  const float* w_dt   = (const float*)d_in[15];
  const float* b_dt   = (const float*)d_in[16];
  const float* A_log  = (const float*)d_in[17];
  const float* D_skip = (const float*)d_in[18];
  const float* w_out  = (const float*)d_in[19];
  const float* nfg    = (const float*)d_in[20];
  const float* nfb    = (const float*)d_in[21];
  (void)in_sizes; (void)n_in; (void)out_size; (void)ws_size;

  char* ws = (char*)d_ws;
  // bf16 weights (all layers)
  __bf16* Wqkv = (__bf16*)(ws + 0);          // 4*1536*512
  __bf16* Wo   = (__bf16*)(ws + 6291456);    // 4*512*512
  __bf16* W1   = (__bf16*)(ws + 8388608);    // 4*2048*512
  __bf16* W2   = (__bf16*)(ws + 16777216);   // 4*512*2048
  __bf16* Win  = (__bf16*)(ws + 25165824);   // 4*2048*512
  __bf16* Wxp  = (__bf16*)(ws + 33554432);   // 4*160*1024
  __bf16* Wdt  = (__bf16*)(ws + 34865152);   // 4*1024*32
  __bf16* Wout = (__bf16*)(ws + 35127296);   // 4*512*1024
  // activations
  __bf16* xb16 = (__bf16*)(ws + 39321600);   // 2048*512
  float*  xf32 = (float*)(ws + 41418752);    // 2048*512
  __bf16* qkvb = (__bf16*)(ws + 45613056);   // 2048*1536 (dead after PV gemm)
  __bf16* vt   = (__bf16*)(ws + 51904512);   // 32*64*512 (dead after PV gemm)
  __bf16* o_b  = (__bf16*)(ws + 54001664);   // 2048*512  (dead after Wo gemm)
  float*  a_f  = (float*)(ws + 56098816);    // 2048*512  (live until out_proj epilogue)
  __bf16* hb   = (__bf16*)(ws + 60293120);   // 2048*512
  float*  h2   = (float*)(ws + 62390272);    // 2048*512 fp32
  // region R1 (32MB, disjoint lifetimes)
  float*  Sf    = (float*)(ws + 66584576);
  float*  xzf   = (float*)(ws + 66584576);
  float*  dtT   = (float*)(ws + 66584576);
  float*  hend0 = (float*)(ws + 74973184);
  float*  uT    = (float*)(ws + 83361792);
  float*  s1T   = (float*)(ws + 91750400);
  // scan summaries overlaying dead regions during scan phases:
  float*  hstart = (float*)(ws + 45613056);  // over qkvb+vt (8MB), dead after PV
  __bf16* yT     = (__bf16*)(ws + 60293120); // over hb+h2[0:2MB] (4MB), dead during scan
  // region R2: P bf16 (16MB) | { xcb b16, xdbl f32/b16, y b16, ffn-mid b16 }
  __bf16* Pb    = (__bf16*)(ws + 100139008); // 32*512*512
  __bf16* xcb   = (__bf16*)(ws + 100139008);               // 2048*1024 bf16
  float*  xdblf = (float*)(ws + 100139008 + 4194304);      // 2048*160
  __bf16* xdblb = (__bf16*)(ws + 100139008 + 5505024);     // 2048*160
  __bf16* yb    = (__bf16*)(ws + 100139008 + 6160384);     // 2048*1024
  __bf16* fb    = (__bf16*)(ws + 100139008 + 10354688);    // 2048*2048 (dead during scan)
  float*  Aprod = (float*)(ws + 110493696);  // over fb (8MB exactly)
  // total = 118882304 bytes (~113.4 MB) -- unchanged

  auto cvt = [&](const float* s, __bf16* dptr, long long n) {
    int n4 = (int)(n / 4);
    cvt_kernel<<<(n4 + 255) / 256, 256, 0, stream>>>(s, dptr, n4);
  };
  cvt(w_qkv, Wqkv, 4LL * 1536 * 512);
  cvt(w_o,   Wo,   4LL * 512 * 512);
  cvt(w1,    W1,   4LL * 2048 * 512);
  cvt(w2,    W2,   4LL * 512 * 2048);
  cvt(w_in,  Win,  4LL * 2048 * 512);
  cvt(w_xp,  Wxp,  4LL * 160 * 1024);
  cvt(w_dt,  Wdt,  4LL * 1024 * 32);
  cvt(w_out, Wout, 4LL * 512 * 1024);

  pe_kernel<<<4096, 256, 0, stream>>>(src, xb16);

  for (int i = 0; i < 4; ++i) {
    // ---- attention branch ----
    launch_gemm_sk(stream, xb16, 512, 0, 0, Wqkv + (size_t)i * 1536 * 512, 512, 0, 0,
                   b_qkv + i * 1536, nullptr, 0, 0, 0,
                   nullptr, 0, 0, 0, qkvb, 1536, 0, 0,
                   2048, 1536, 512, 1, 1, 1.f, 0);
    transpose_v_kernel<<<32, 256, 0, stream>>>(qkvb, vt);
    launch_gemm(stream, qkvb, 1536, 512LL * 1536, 64, qkvb + 512, 1536, 512LL * 1536, 64,
                nullptr, nullptr, 0, 0, 0,
                Sf, 512, 2097152LL, 262144LL, nullptr, 0, 0, 0,
                512, 512, 64, 32, 8, 0.125f, 0);
    softmax_kernel<<<4096, 256, 0, stream>>>(Sf, Pb);
    launch_gemm_sk(stream, Pb, 512, 2097152LL, 262144LL, vt, 512, 262144LL, 32768LL,
                   nullptr, nullptr, 0, 0, 0,
                   nullptr, 0, 0, 0, o_b, 512, 262144LL, 64LL,
                   512, 64, 512, 32, 8, 1.f, 0);
    launch_gemm_sk(stream, o_b, 512, 0, 0, Wo + (size_t)i * 512 * 512, 512, 0, 0,
                   b_o + i * 512, nullptr, 0, 0, 0,
                   a_f, 512, 0, 0, nullptr, 0, 0, 0,
                   2048, 512, 512, 1, 1, 1.f, 0);
    // ---- mamba branch ----
    launch_gemm_sk(stream, xb16, 512, 0, 0, Win + (size_t)i * 2048 * 512, 512, 0, 0,
                   nullptr, nullptr, 0, 0, 0,
                   xzf, 2048, 0, 0, nullptr, 0, 0, 0,
                   2048, 2048, 512, 1, 1, 1.f, 0);
    conv_silu_t_kernel<<<dim3(16, 8, 4), 256, 0, stream>>>(
        xzf, conv_w + i * 1024 * 4, conv_b + i * 1024, xcb, uT, s1T);
    launch_gemm_sk(stream, xcb, 1024, 0, 0, Wxp + (size_t)i * 160 * 1024, 1024, 0, 0,
                   nullptr, nullptr, 0, 0, 0,
                   xdblf, 160, 0, 0, xdblb, 160, 0, 0,
                   2048, 160, 1024, 1, 1, 1.f, 0);
    // dt = softplus(dt_in @ Wdt^T + b_dt) -> TRANSPOSED into dtT (old kernel, ct=1)
    launch_gemm(stream, xdblb, 160, 0, 0, Wdt + (size_t)i * 1024 * 32, 32, 0, 0,
                b_dt + i * 1024, nullptr, 0, 0, 0,
                dtT, 2048, 0, 0, nullptr, 0, 0, 0,
                2048, 1024, 32, 1, 1, 1.f, 2, /*ct=*/1);
    // chunked scan: 3 phases + transpose
    scan_p1_kernel<<<8192, 256, 0, stream>>>(dtT, uT, xdblf,
                                             A_log + (size_t)i * 1024 * 64, Aprod, hend0);
    scan_p2_kernel<<<1024, 256, 0, stream>>>(Aprod, hend0, hstart);
    scan_p3_kernel<<<16384, 128, 0, stream>>>(dtT, uT, s1T, xdblf,
                                              A_log + (size_t)i * 1024 * 64,
                                              D_skip + i * 1024, hstart, yT);
    transpose_y_kernel<<<dim3(16, 32), 256, 0, stream>>>(yT, yb);
    launch_gemm_sk(stream, yb, 1024, 0, 0, Wout + (size_t)i * 512 * 1024, 1024, 0, 0,
                   nullptr, a_f, 512, 0, 0,
                   nullptr, 0, 0, 0, hb, 512, 0, 0,
                   2048, 512, 1024, 1, 1, 1.f, 0);
    // ---- FFN + LN ----
    launch_gemm_sk(stream, hb, 512, 0, 0, W1 + (size_t)i * 2048 * 512, 512, 0, 0,
                   b1 + i * 2048, nullptr, 0, 0, 0,
                   nullptr, 0, 0, 0, fb, 2048, 0, 0,
                   2048, 2048, 512, 1, 1, 1.f, 1);
    launch_gemm_sk(stream, fb, 2048, 0, 0, W2 + (size_t)i * 512 * 2048, 2048, 0, 0,
                   b2 + i * 512, nullptr, 0, 0, 0,
                   h2, 512, 0, 0, nullptr, 0, 0, 0,
                   2048, 512, 2048, 1, 1, 1.f, 0);
    layernorm_kernel<<<512, 256, 0, stream>>>(h2, n1g + i * 512, n1b + i * 512, xf32, xb16);
  }
  // final layernorm -> d_out (fp32)
  layernorm_kernel<<<512, 256, 0, stream>>>(xf32, nfg, nfb, (float*)d_out, nullptr);
}